// Round 9
// baseline (165.846 us; speedup 1.0000x reference)
//
#include <hip/hip_runtime.h>

typedef _Float16 half8 __attribute__((ext_vector_type(8)));
typedef float floatx4 __attribute__((ext_vector_type(4)));
typedef int intx4 __attribute__((ext_vector_type(4)));
typedef int intx8 __attribute__((ext_vector_type(8)));

#define SCALE_POS 2.0f
#define SCALE_NEG 40.0f
#define THRESH 0.5f
#define MARGIN 0.1f
#define EPSV 1e-5f

// =====================================================================
// kernel 1 (R25): MX-fp8 symmetric GEMM over FULL 128x128 tiles with
// FUSED fp32->fp8 conversion in the staging path (k_init deleted).
// 528 blocks x 256 thr (4 waves 2x2) — the R23/R20 measured-best
// structure. Staging (R21-verified reg-stage scheme): linear coalesced
// fp32 loads of feats -> __builtin_amdgcn_cvt_pk_fp8_f32 (same RNE
// instructions as the old k_init => bit-identical fp8 => identical
// sim values) -> ds_write_b128 to the same XOR-swizzled LDS layout.
// The 4 MB f8 intermediate and its 16MB-read/4MB-write dispatch are
// gone (4 -> 3 dispatches). feats = 16 MB (L3-resident; 512 KB panels
// L2-resident under the XCD swizzle). Everything downstream of LDS —
// fragments, MFMA, simh layout, unique-writer stat partials — is
// R23-verbatim.
// =====================================================================
__global__ void __launch_bounds__(256, 2)
k_gemm_h(const float* __restrict__ feats,
         const int* __restrict__ labels,
         float* __restrict__ pmin,     // [64][B] partial min-pos
         float* __restrict__ pmax,     // [64][B] partial max-neg
         _Float16* __restrict__ simh,
         float* __restrict__ out,      // zeroed here (bid0==0)
         int D, int nb) {      // D = 1024 elements/row
    __shared__ __align__(16) unsigned char As[128 * 128];  // 16 KB
    __shared__ __align__(16) unsigned char Bs[128 * 128];  // 16 KB
    __shared__ int labR[128], labC[128];

    const int Bsz = nb * 128;

    // bijective XCD-aware swizzle: 528 tiles = 8 XCDs x 66
    const int bid0 = blockIdx.x;
    const int t = (bid0 & 7) * 66 + (bid0 >> 3);
    int rb = 0, rem = t;
    while (rem >= nb - rb) { rem -= nb - rb; ++rb; }
    const int cb = rb + rem;
    const int rowBase = rb * 128;
    const int colBase = cb * 128;

    const int tid = threadIdx.x;        // 0..255
    const int lane = tid & 63;
    const int wave = tid >> 6;          // 0..3
    const int wr = wave >> 1;           // row half of output tile
    const int wc = wave & 1;            // col half of output tile
    const int q = lane >> 4;
    const int cIn = lane & 15;

    if (bid0 == 0 && tid == 0) out[0] = 0.f;   // k_final accumulates later

    if (tid < 128) labR[tid] = labels[rowBase + tid];
    else           labC[tid - 128] = labels[colBase + (tid - 128)];

    // staging: 32 chunks of 1KB fp8 (8 rows x 128B). Wave handles 8.
    // lane L: row c*8+(L>>3); logical 16B-fp8-block (L&7) = 16 floats;
    // LDS phys block = (L&7)^subrow (row-XOR swizzle, R21-verified).
    const int subrow = lane >> 3;            // 0..7
    const int blk = lane & 7;                // logical 16B block
    const float* gF[8];
    int wOff[8];
#pragma unroll
    for (int j = 0; j < 8; ++j) {
        const int c = wave * 8 + j;          // 0..31
        const int grow = (c < 16) ? (rowBase + c * 8 + subrow)
                                  : (colBase + (c - 16) * 8 + subrow);
        gF[j] = feats + (size_t)grow * D + blk * 16;
        wOff[j] = c * 1024 + subrow * 128 + ((blk ^ subrow) << 4);
    }

    // fragment LDS offsets: row r, 32B k-group q = logical blocks 2q,2q+1
    // physical p = blk ^ (r&7)   (unchanged from R19..R23)
    int aOff0[4], aOff1[4], bOff0[4], bOff1[4];
#pragma unroll
    for (int i = 0; i < 4; ++i) {
        const int rA = wr * 64 + i * 16 + cIn;
        aOff0[i] = rA * 128 + ((2 * q) ^ (rA & 7)) * 16;
        aOff1[i] = rA * 128 + ((2 * q + 1) ^ (rA & 7)) * 16;
        const int rB = wc * 64 + i * 16 + cIn;
        bOff0[i] = rB * 128 + ((2 * q) ^ (rB & 7)) * 16;
        bOff1[i] = rB * 128 + ((2 * q + 1) ^ (rB & 7)) * 16;
    }

    floatx4 acc[4][4] = {};

    const int KT = D >> 7;               // 8 iters of K=128
    for (int kt = 0; kt < KT; ++kt) {
        __syncthreads();                 // prev readers done (+labels at kt=0)
        // ---- stage-with-convert: fp32 loads -> cvt_pk_fp8 -> ds_write ----
#pragma unroll
        for (int j = 0; j < 8; ++j) {
            const floatx4* sp = (const floatx4*)(gF[j] + kt * 128);
            floatx4 f0 = sp[0], f1 = sp[1], f2 = sp[2], f3 = sp[3];
            int w0 = 0, w1 = 0, w2 = 0, w3 = 0;
            w0 = __builtin_amdgcn_cvt_pk_fp8_f32(f0[0], f0[1], w0, false);
            w0 = __builtin_amdgcn_cvt_pk_fp8_f32(f0[2], f0[3], w0, true);
            w1 = __builtin_amdgcn_cvt_pk_fp8_f32(f1[0], f1[1], w1, false);
            w1 = __builtin_amdgcn_cvt_pk_fp8_f32(f1[2], f1[3], w1, true);
            w2 = __builtin_amdgcn_cvt_pk_fp8_f32(f2[0], f2[1], w2, false);
            w2 = __builtin_amdgcn_cvt_pk_fp8_f32(f2[2], f2[3], w2, true);
            w3 = __builtin_amdgcn_cvt_pk_fp8_f32(f3[0], f3[1], w3, false);
            w3 = __builtin_amdgcn_cvt_pk_fp8_f32(f3[2], f3[3], w3, true);
            intx4 v = {w0, w1, w2, w3};
            *(intx4*)(((wOff[j] < 16384) ? As : (Bs - 16384)) + wOff[j]) = v;
        }
        __syncthreads();                 // staged tile visible

        intx8 a[4], b[4];
#pragma unroll
        for (int i = 0; i < 4; ++i) {
            intx4 lo = *(const intx4*)(As + aOff0[i]);
            intx4 hi = *(const intx4*)(As + aOff1[i]);
            a[i] = __builtin_shufflevector(lo, hi, 0, 1, 2, 3, 4, 5, 6, 7);
        }
#pragma unroll
        for (int i = 0; i < 4; ++i) {
            intx4 lo = *(const intx4*)(Bs + bOff0[i]);
            intx4 hi = *(const intx4*)(Bs + bOff1[i]);
            b[i] = __builtin_shufflevector(lo, hi, 0, 1, 2, 3, 4, 5, 6, 7);
        }
#pragma unroll
        for (int i = 0; i < 4; ++i)
#pragma unroll
            for (int j2 = 0; j2 < 4; ++j2)
                acc[i][j2] = __builtin_amdgcn_mfma_scale_f32_16x16x128_f8f6f4(
                    a[i], b[j2], acc[i][j2], 0, 0,       // cbsz=fp8, blgp=fp8
                    0, 0x7f7f7f7f,                       // opsel_a, scale_a (unity E8M0)
                    0, 0x7f7f7f7f);                      // opsel_b, scale_b
    }

    int rLabv[16];
#pragma unroll
    for (int mi = 0; mi < 4; ++mi)
#pragma unroll
        for (int rr = 0; rr < 4; ++rr)
            rLabv[mi * 4 + rr] = labR[wr * 64 + mi * 16 + q * 4 + rr];
    int cLabv[4];
#pragma unroll
    for (int ni = 0; ni < 4; ++ni)
        cLabv[ni] = labC[wc * 64 + ni * 16 + cIn];

    // ---- fp16 store: identical per-64-col-half layout to R13..R23 ----
    {
        half8* dst = (half8*)(simh + (size_t)(2 * t + wc) * 8192
                                   + (size_t)(wr * 64 + lane) * 64);
#pragma unroll
        for (int mi = 0; mi < 4; ++mi) {
            half8 h0, h1;
#pragma unroll
            for (int ni = 0; ni < 2; ++ni)
#pragma unroll
                for (int rr = 0; rr < 4; ++rr) {
                    h0[ni * 4 + rr] = (_Float16)acc[mi][ni][rr];
                    h1[ni * 4 + rr] = (_Float16)acc[mi][ni + 2][rr];
                }
            dst[mi * 2] = h0;
            dst[mi * 2 + 1] = h1;
        }
    }

    // ---- row stats partials: slot (2*cb+wc), plain stores ----
    {
        float* pmnRow = pmin + (size_t)(2 * cb + wc) * Bsz + rowBase;
        float* pmxRow = pmax + (size_t)(2 * cb + wc) * Bsz + rowBase;
#pragma unroll
        for (int mi = 0; mi < 4; ++mi)
#pragma unroll
            for (int rr = 0; rr < 4; ++rr) {
                const int rLoc = wr * 64 + mi * 16 + q * 4 + rr;
                const int rLab = rLabv[mi * 4 + rr];
                float vmin = 1e30f, vmax = -1e30f;
#pragma unroll
                for (int ni = 0; ni < 4; ++ni) {
                    float s = acc[mi][ni][rr];
                    if (rLab == cLabv[ni]) {
                        if (s < 1.0f - EPSV) vmin = fminf(vmin, s);
                    } else {
                        vmax = fmaxf(vmax, s);
                    }
                }
#pragma unroll
                for (int off = 8; off; off >>= 1) {
                    vmin = fminf(vmin, __shfl_xor(vmin, off, 16));
                    vmax = fmaxf(vmax, __shfl_xor(vmax, off, 16));
                }
                if (cIn == 0) {
                    pmnRow[rLoc] = vmin;
                    pmxRow[rLoc] = vmax;
                }
            }
    }

    // ---- col stats partials via symmetry (off-diag only): slot (2*rb+wr) ----
    if (rb != cb) {
        float* pmnCol = pmin + (size_t)(2 * rb + wr) * Bsz + colBase;
        float* pmxCol = pmax + (size_t)(2 * rb + wr) * Bsz + colBase;
#pragma unroll
        for (int ni = 0; ni < 4; ++ni) {
            const int cLab = cLabv[ni];
            float vmin = 1e30f, vmax = -1e30f;
#pragma unroll
            for (int mi = 0; mi < 4; ++mi)
#pragma unroll
                for (int rr = 0; rr < 4; ++rr) {
                    float s = acc[mi][ni][rr];
                    if (rLabv[mi * 4 + rr] == cLab) {
                        if (s < 1.0f - EPSV) vmin = fminf(vmin, s);
                    } else {
                        vmax = fmaxf(vmax, s);
                    }
                }
            vmin = fminf(vmin, __shfl_xor(vmin, 16, 64));
            vmin = fminf(vmin, __shfl_xor(vmin, 32, 64));
            vmax = fmaxf(vmax, __shfl_xor(vmax, 16, 64));
            vmax = fmaxf(vmax, __shfl_xor(vmax, 32, 64));
            if (q == 0) {
                const int cLoc = wc * 64 + ni * 16 + cIn;
                pmnCol[cLoc] = vmin;
                pmxCol[cLoc] = vmax;
            }
        }
    }
}

// =====================================================================
// kernel 2 (R23 verbatim): pass 2 with fused gate prologue (64 slots),
// then the verified gated-exp-sum body -> unique-writer psP/psN.
// =====================================================================
__global__ void __launch_bounds__(256)
k_sum2f(const _Float16* __restrict__ simh,
        const int* __restrict__ labels,
        const float* __restrict__ pmin,
        const float* __restrict__ pmax,
        float* __restrict__ psP, float* __restrict__ psN,
        int nb, int B) {
    __shared__ int labR[128], labC[128];
    __shared__ float gNR[128], gPR[128], gNC[128], gPC[128];

    int t = blockIdx.x;
    int rb = 0, rem = t;
    while (rem >= nb - rb) { rem -= nb - rb; ++rb; }
    const int cb = rb + rem;
    const int rowBase = rb * 128;

    const int tid = threadIdx.x;
    const int sub = tid >> 7;           // 0..1 : col half
    const int stid = tid & 127;
    const int wave = stid >> 6;         // 0..1 : row half within sub
    const int lane = tid & 63;
    const int q = lane >> 4;
    const int cIn = lane & 15;
    const int colBase = cb * 128 + sub * 64;

    // ---- fused gate prologue ----
    {
        const int j = tid & 127;
        const int base = (tid < 128) ? (rowBase + j) : (cb * 128 + j);
        float mn = 1e30f, mx = -1e30f;
#pragma unroll 4
        for (int k = 0; k < 64; ++k) {
            mn = fminf(mn, pmin[(size_t)k * B + base]);
            mx = fmaxf(mx, pmax[(size_t)k * B + base]);
        }
        if (tid < 128) {
            labR[j] = labels[rowBase + j];
            gNR[j] = mn - MARGIN;       // neg kept if s > gNR
            gPR[j] = mx + MARGIN;       // pos kept if s < gPR
        } else {
            labC[j] = labels[cb * 128 + j];
            gNC[j] = mn - MARGIN;
            gPC[j] = mx + MARGIN;
        }
    }
    __syncthreads();

    int cLabv[4];
    float gNCv[4], gPCv[4];
#pragma unroll
    for (int ni = 0; ni < 4; ++ni) {
        const int j = sub * 64 + ni * 16 + cIn;
        cLabv[ni] = labC[j];
        gNCv[ni] = gNC[j];
        gPCv[ni] = gPC[j];
    }

    const half8* src = (const half8*)(simh + (size_t)(2 * t + sub) * 8192 + (size_t)stid * 64);
    half8 hv[8];
#pragma unroll
    for (int v = 0; v < 8; ++v) hv[v] = src[v];

    float cps[4] = {}, cns[4] = {};
    const bool offd = (rb != cb);

    float* psPRow = psP + (size_t)(2 * cb + sub) * B + rowBase;
    float* psNRow = psN + (size_t)(2 * cb + sub) * B + rowBase;

#pragma unroll
    for (int mi = 0; mi < 4; ++mi)
#pragma unroll
        for (int rr = 0; rr < 4; ++rr) {
            const int rLoc = wave * 64 + mi * 16 + q * 4 + rr;
            const int rLab = labR[rLoc];
            const float gn = gNR[rLoc];
            const float gp = gPR[rLoc];
            float rp = 0.f, rn = 0.f;
#pragma unroll
            for (int ni = 0; ni < 4; ++ni) {
                const int idx = mi * 16 + ni * 4 + rr;
                const float s = (float)hv[idx >> 3][idx & 7];
                if (rLab == cLabv[ni]) {
                    if (s < 1.0f - EPSV) {
                        float ev = __expf(-SCALE_POS * (s - THRESH));
                        if (s < gp) rp += ev;
                        if (offd && s < gPCv[ni]) cps[ni] += ev;
                    }
                } else {
                    float ev = __expf(SCALE_NEG * (s - THRESH));
                    if (s > gn) rn += ev;
                    if (offd && s > gNCv[ni]) cns[ni] += ev;
                }
            }
#pragma unroll
            for (int off = 8; off; off >>= 1) {
                rp += __shfl_xor(rp, off, 16);
                rn += __shfl_xor(rn, off, 16);
            }
            if (cIn == 0) {
                psPRow[rLoc] = rp;      // unique slot, plain store
                psNRow[rLoc] = rn;
            }
        }
    if (offd) {
        float* psPCol = psP + (size_t)(2 * rb + wave) * B + colBase;
        float* psNCol = psN + (size_t)(2 * rb + wave) * B + colBase;
#pragma unroll
        for (int ni = 0; ni < 4; ++ni) {
            cps[ni] += __shfl_xor(cps[ni], 16, 64);
            cps[ni] += __shfl_xor(cps[ni], 32, 64);
            cns[ni] += __shfl_xor(cns[ni], 16, 64);
            cns[ni] += __shfl_xor(cns[ni], 32, 64);
            if (q == 0) {
                const int cLoc = ni * 16 + cIn;
                psPCol[cLoc] = cps[ni];
                psNCol[cLoc] = cns[ni];
            }
        }
    }
}

// =====================================================================
// kernel 3: final reduce -> out[0] (16 blocks, one atomicAdd each;
// out zeroed by k_gemm_h, stream-ordered)
// =====================================================================
__global__ void __launch_bounds__(256)
k_final(const float* __restrict__ psP, const float* __restrict__ psN,
        float* __restrict__ out, int B) {
    __shared__ float red[4];
    const int r = blockIdx.x * 256 + threadIdx.x;
    float P = 0.f, N = 0.f;
    for (int k = 0; k < 64; ++k) {
        P += psP[(size_t)k * B + r];
        N += psN[(size_t)k * B + r];
    }
    float a = (P > 0.f && N > 0.f)
                  ? log1pf(P) * (1.0f / SCALE_POS) + log1pf(N) * (1.0f / SCALE_NEG)
                  : 0.f;
#pragma unroll
    for (int off = 32; off; off >>= 1) a += __shfl_down(a, off, 64);
    const int tid = threadIdx.x;
    if ((tid & 63) == 0) red[tid >> 6] = a;
    __syncthreads();
    if (tid == 0)
        atomicAdd(out, (red[0] + red[1] + red[2] + red[3]) / (float)B);
}

extern "C" void kernel_launch(void* const* d_in, const int* in_sizes, int n_in,
                              void* d_out, int out_size, void* d_ws, size_t ws_size,
                              hipStream_t stream) {
    const float* feats = (const float*)d_in[0];
    const int* labels = (const int*)d_in[1];
    const int B = in_sizes[1];            // 4096
    const int D = in_sizes[0] / B;        // 1024
    const int nb = B / 128;               // 32
    const int NT = nb * (nb + 1) / 2;     // 528

    char* ws = (char*)d_ws;
    size_t off = 0;
    float* pmin = (float*)(ws + off); off += (size_t)64 * B * 4;   // 1 MB
    float* pmax = (float*)(ws + off); off += (size_t)64 * B * 4;   // 1 MB
    float* psP  = (float*)(ws + off); off += (size_t)64 * B * 4;   // 1 MB
    float* psN  = (float*)(ws + off); off += (size_t)64 * B * 4;   // 1 MB
    _Float16* simh = (_Float16*)(ws + ((off + 255) & ~(size_t)255));
    float* outp = (float*)d_out;

    // 528 blocks x 256 thr — GEMM with fused fp32->fp8 staging (R25)
    k_gemm_h<<<NT, 256, 0, stream>>>(feats, labels, pmin, pmax, simh, outp, D, nb);

    // pass 2: 528 blocks x 256 thr, fused gate prologue + partial-slot sums
    k_sum2f<<<NT, 256, 0, stream>>>(simh, labels, pmin, pmax, psP, psN, nb, B);

    // final: 16 blocks, one atomic each
    k_final<<<B / 256, 256, 0, stream>>>(psP, psN, outp, B);
}

// Round 10
// 136.269 us; speedup vs baseline: 1.2170x; 1.2170x over previous
//
#include <hip/hip_runtime.h>

typedef _Float16 half8 __attribute__((ext_vector_type(8)));
typedef float floatx4 __attribute__((ext_vector_type(4)));
typedef int intx4 __attribute__((ext_vector_type(4)));
typedef int intx8 __attribute__((ext_vector_type(8)));
typedef __attribute__((address_space(1))) const void gvoid;
typedef __attribute__((address_space(3))) void svoid;

#define SCALE_POS 2.0f
#define SCALE_NEG 40.0f
#define THRESH 0.5f
#define MARGIN 0.1f
#define EPSV 1e-5f

// ---- kernel 1: fp32 -> fp8 e4m3 (OCP, RNE via HW cvt) + out zero ----
__global__ void k_init(const float* __restrict__ feats,
                       unsigned char* __restrict__ f8,
                       float* __restrict__ out,
                       int total4) {
    int i = blockIdx.x * blockDim.x + threadIdx.x;
    if (i < total4) {
        float4 v = ((const float4*)feats)[i];
        int w = 0;
        w = __builtin_amdgcn_cvt_pk_fp8_f32(v.x, v.y, w, false);  // bytes 0,1
        w = __builtin_amdgcn_cvt_pk_fp8_f32(v.z, v.w, w, true);   // bytes 2,3
        ((int*)f8)[i] = w;
    }
    if (i == 0) out[0] = 0.f;
}

// =====================================================================
// kernel 2 (R26 = R23 GEMM with TRANSPOSED stat partials [B][64]):
// MX-fp8 symmetric GEMM over FULL 128x128 tiles, 528 blocks x 256 thr
// (4 waves 2x2), gload_lds staging, XCD swizzle. Stat partial writes
// go to pmin/pmax[r*64 + slot] (scattered singles, same as before);
// the TRANSPOSE pays off on the read side (k_sum2f gate prologue and
// k_final become contiguous 256B-per-row vector reads with XCD-local
// stripes — R25's lesson: phase time tracks global round-trip traffic
// at ~0.5 TB/s effective, and the [64][B] gate reads were ~25MB FETCH).
// =====================================================================
__global__ void __launch_bounds__(256, 4)
k_gemm_h(const unsigned char* __restrict__ f8,
         const int* __restrict__ labels,
         float* __restrict__ pmin,     // [B][64] partial min-pos
         float* __restrict__ pmax,     // [B][64] partial max-neg
         _Float16* __restrict__ simh,
         int D, int nb) {      // D = 1024 elements = 1024 bytes/row
    __shared__ __align__(16) unsigned char As[128 * 128];  // 16 KB
    __shared__ __align__(16) unsigned char Bs[128 * 128];  // 16 KB
    __shared__ int labR[128], labC[128];

    // bijective XCD-aware swizzle: 528 tiles = 8 XCDs x 66
    const int bid0 = blockIdx.x;
    const int t = (bid0 & 7) * 66 + (bid0 >> 3);
    int rb = 0, rem = t;
    while (rem >= nb - rb) { rem -= nb - rb; ++rb; }
    const int cb = rb + rem;
    const int rowBase = rb * 128;
    const int colBase = cb * 128;

    const int tid = threadIdx.x;        // 0..255
    const int lane = tid & 63;
    const int wave = tid >> 6;          // 0..3
    const int wr = wave >> 1;           // row half of output tile
    const int wc = wave & 1;            // col half of output tile
    const int q = lane >> 4;
    const int cIn = lane & 15;

    if (tid < 128) labR[tid] = labels[rowBase + tid];
    else           labC[tid - 128] = labels[colBase + (tid - 128)];

    // staging: 32 chunks of 1KB (8 rows x 128B). Wave handles 8.
    const int subrow = lane >> 3;
    const int swz = (lane & 7) ^ subrow;     // logical 16B-block index
    const unsigned char* gP[8];
    unsigned char* lP[8];
#pragma unroll
    for (int j = 0; j < 8; ++j) {
        const int c = wave * 8 + j;          // 0..31
        const int grow = (c < 16) ? (rowBase + c * 8 + subrow)
                                  : (colBase + (c - 16) * 8 + subrow);
        gP[j] = f8 + (size_t)grow * D + swz * 16;
        lP[j] = ((c < 16) ? (As + c * 1024) : (Bs + (c - 16) * 1024)) + lane * 16;
    }

    // fragment LDS offsets: row r, 32B k-group q = logical blocks 2q,2q+1
    // physical p = blk ^ (r&7)
    int aOff0[4], aOff1[4], bOff0[4], bOff1[4];
#pragma unroll
    for (int i = 0; i < 4; ++i) {
        const int rA = wr * 64 + i * 16 + cIn;
        aOff0[i] = rA * 128 + ((2 * q) ^ (rA & 7)) * 16;
        aOff1[i] = rA * 128 + ((2 * q + 1) ^ (rA & 7)) * 16;
        const int rB = wc * 64 + i * 16 + cIn;
        bOff0[i] = rB * 128 + ((2 * q) ^ (rB & 7)) * 16;
        bOff1[i] = rB * 128 + ((2 * q + 1) ^ (rB & 7)) * 16;
    }

    floatx4 acc[4][4] = {};

    const int KT = D >> 7;               // 8 iters of K=128
    for (int kt = 0; kt < KT; ++kt) {
        const int kOff = kt * 128;
        __syncthreads();                 // prev readers done (+labels at kt=0)
#pragma unroll
        for (int j = 0; j < 8; ++j)
            __builtin_amdgcn_global_load_lds((gvoid*)(gP[j] + kOff), (svoid*)lP[j], 16, 0, 0);
        __syncthreads();                 // stage landed (implicit vmcnt drain)

        intx8 a[4], b[4];
#pragma unroll
        for (int i = 0; i < 4; ++i) {
            intx4 lo = *(const intx4*)(As + aOff0[i]);
            intx4 hi = *(const intx4*)(As + aOff1[i]);
            a[i] = __builtin_shufflevector(lo, hi, 0, 1, 2, 3, 4, 5, 6, 7);
        }
#pragma unroll
        for (int i = 0; i < 4; ++i) {
            intx4 lo = *(const intx4*)(Bs + bOff0[i]);
            intx4 hi = *(const intx4*)(Bs + bOff1[i]);
            b[i] = __builtin_shufflevector(lo, hi, 0, 1, 2, 3, 4, 5, 6, 7);
        }
#pragma unroll
        for (int i = 0; i < 4; ++i)
#pragma unroll
            for (int j2 = 0; j2 < 4; ++j2)
                acc[i][j2] = __builtin_amdgcn_mfma_scale_f32_16x16x128_f8f6f4(
                    a[i], b[j2], acc[i][j2], 0, 0,       // cbsz=fp8, blgp=fp8
                    0, 0x7f7f7f7f,                       // opsel_a, scale_a (unity E8M0)
                    0, 0x7f7f7f7f);                      // opsel_b, scale_b
    }

    int rLabv[16];
#pragma unroll
    for (int mi = 0; mi < 4; ++mi)
#pragma unroll
        for (int rr = 0; rr < 4; ++rr)
            rLabv[mi * 4 + rr] = labR[wr * 64 + mi * 16 + q * 4 + rr];
    int cLabv[4];
#pragma unroll
    for (int ni = 0; ni < 4; ++ni)
        cLabv[ni] = labC[wc * 64 + ni * 16 + cIn];

    // ---- fp16 store: identical per-64-col-half layout to R13..R23 ----
    {
        half8* dst = (half8*)(simh + (size_t)(2 * t + wc) * 8192
                                   + (size_t)(wr * 64 + lane) * 64);
#pragma unroll
        for (int mi = 0; mi < 4; ++mi) {
            half8 h0, h1;
#pragma unroll
            for (int ni = 0; ni < 2; ++ni)
#pragma unroll
                for (int rr = 0; rr < 4; ++rr) {
                    h0[ni * 4 + rr] = (_Float16)acc[mi][ni][rr];
                    h1[ni * 4 + rr] = (_Float16)acc[mi][ni + 2][rr];
                }
            dst[mi * 2] = h0;
            dst[mi * 2 + 1] = h1;
        }
    }

    // ---- row stats partials: pmin[r][slot 2*cb+wc], plain stores ----
    {
        const int slotR = 2 * cb + wc;
#pragma unroll
        for (int mi = 0; mi < 4; ++mi)
#pragma unroll
            for (int rr = 0; rr < 4; ++rr) {
                const int rLoc = wr * 64 + mi * 16 + q * 4 + rr;
                const int rLab = rLabv[mi * 4 + rr];
                float vmin = 1e30f, vmax = -1e30f;
#pragma unroll
                for (int ni = 0; ni < 4; ++ni) {
                    float s = acc[mi][ni][rr];
                    if (rLab == cLabv[ni]) {
                        if (s < 1.0f - EPSV) vmin = fminf(vmin, s);
                    } else {
                        vmax = fmaxf(vmax, s);
                    }
                }
#pragma unroll
                for (int off = 8; off; off >>= 1) {
                    vmin = fminf(vmin, __shfl_xor(vmin, off, 16));
                    vmax = fmaxf(vmax, __shfl_xor(vmax, off, 16));
                }
                if (cIn == 0) {
                    pmin[(size_t)(rowBase + rLoc) * 64 + slotR] = vmin;
                    pmax[(size_t)(rowBase + rLoc) * 64 + slotR] = vmax;
                }
            }
    }

    // ---- col stats partials via symmetry (off-diag only): slot 2*rb+wr ----
    if (rb != cb) {
        const int slotC = 2 * rb + wr;
#pragma unroll
        for (int ni = 0; ni < 4; ++ni) {
            const int cLab = cLabv[ni];
            float vmin = 1e30f, vmax = -1e30f;
#pragma unroll
            for (int mi = 0; mi < 4; ++mi)
#pragma unroll
                for (int rr = 0; rr < 4; ++rr) {
                    float s = acc[mi][ni][rr];
                    if (rLabv[mi * 4 + rr] == cLab) {
                        if (s < 1.0f - EPSV) vmin = fminf(vmin, s);
                    } else {
                        vmax = fmaxf(vmax, s);
                    }
                }
            vmin = fminf(vmin, __shfl_xor(vmin, 16, 64));
            vmin = fminf(vmin, __shfl_xor(vmin, 32, 64));
            vmax = fmaxf(vmax, __shfl_xor(vmax, 16, 64));
            vmax = fmaxf(vmax, __shfl_xor(vmax, 32, 64));
            if (q == 0) {
                const int cLoc = wc * 64 + ni * 16 + cIn;
                pmin[(size_t)(colBase + cLoc) * 64 + slotC] = vmin;
                pmax[(size_t)(colBase + cLoc) * 64 + slotC] = vmax;
            }
        }
    }
}

// =====================================================================
// kernel 3 (R26): pass 2 with fused gate prologue reading TRANSPOSED
// [B][64] partials — 16 x float4 contiguous loads per thread, stripes
// XCD-local under the swizzle. Then the verified gated-exp-sum body;
// psP/psN also [B][64] (scattered single-float writes, same as before).
// =====================================================================
__global__ void __launch_bounds__(256)
k_sum2f(const _Float16* __restrict__ simh,
        const int* __restrict__ labels,
        const float* __restrict__ pmin,
        const float* __restrict__ pmax,
        float* __restrict__ psP, float* __restrict__ psN,
        int nb, int B) {
    __shared__ int labR[128], labC[128];
    __shared__ float gNR[128], gPR[128], gNC[128], gPC[128];

    int t = blockIdx.x;
    int rb = 0, rem = t;
    while (rem >= nb - rb) { rem -= nb - rb; ++rb; }
    const int cb = rb + rem;
    const int rowBase = rb * 128;

    const int tid = threadIdx.x;
    const int sub = tid >> 7;           // 0..1 : col half
    const int stid = tid & 127;
    const int wave = stid >> 6;         // 0..1 : row half within sub
    const int lane = tid & 63;
    const int q = lane >> 4;
    const int cIn = lane & 15;
    const int colBase = cb * 128 + sub * 64;

    // ---- fused gate prologue: contiguous 256B per thread ----
    {
        const int j = tid & 127;
        const int base = (tid < 128) ? (rowBase + j) : (cb * 128 + j);
        const floatx4* pm = (const floatx4*)(pmin + (size_t)base * 64);
        const floatx4* px = (const floatx4*)(pmax + (size_t)base * 64);
        float mn = 1e30f, mx = -1e30f;
#pragma unroll
        for (int k = 0; k < 16; ++k) {
            floatx4 a = pm[k];
            floatx4 b = px[k];
            mn = fminf(mn, fminf(fminf(a[0], a[1]), fminf(a[2], a[3])));
            mx = fmaxf(mx, fmaxf(fmaxf(b[0], b[1]), fmaxf(b[2], b[3])));
        }
        if (tid < 128) {
            labR[j] = labels[rowBase + j];
            gNR[j] = mn - MARGIN;       // neg kept if s > gNR
            gPR[j] = mx + MARGIN;       // pos kept if s < gPR
        } else {
            labC[j] = labels[cb * 128 + j];
            gNC[j] = mn - MARGIN;
            gPC[j] = mx + MARGIN;
        }
    }
    __syncthreads();

    int cLabv[4];
    float gNCv[4], gPCv[4];
#pragma unroll
    for (int ni = 0; ni < 4; ++ni) {
        const int j = sub * 64 + ni * 16 + cIn;
        cLabv[ni] = labC[j];
        gNCv[ni] = gNC[j];
        gPCv[ni] = gPC[j];
    }

    const half8* src = (const half8*)(simh + (size_t)(2 * t + sub) * 8192 + (size_t)stid * 64);
    half8 hv[8];
#pragma unroll
    for (int v = 0; v < 8; ++v) hv[v] = src[v];

    float cps[4] = {}, cns[4] = {};
    const bool offd = (rb != cb);

    const int slotR = 2 * cb + sub;

#pragma unroll
    for (int mi = 0; mi < 4; ++mi)
#pragma unroll
        for (int rr = 0; rr < 4; ++rr) {
            const int rLoc = wave * 64 + mi * 16 + q * 4 + rr;
            const int rLab = labR[rLoc];
            const float gn = gNR[rLoc];
            const float gp = gPR[rLoc];
            float rp = 0.f, rn = 0.f;
#pragma unroll
            for (int ni = 0; ni < 4; ++ni) {
                const int idx = mi * 16 + ni * 4 + rr;
                const float s = (float)hv[idx >> 3][idx & 7];
                if (rLab == cLabv[ni]) {
                    if (s < 1.0f - EPSV) {
                        float ev = __expf(-SCALE_POS * (s - THRESH));
                        if (s < gp) rp += ev;
                        if (offd && s < gPCv[ni]) cps[ni] += ev;
                    }
                } else {
                    float ev = __expf(SCALE_NEG * (s - THRESH));
                    if (s > gn) rn += ev;
                    if (offd && s > gNCv[ni]) cns[ni] += ev;
                }
            }
#pragma unroll
            for (int off = 8; off; off >>= 1) {
                rp += __shfl_xor(rp, off, 16);
                rn += __shfl_xor(rn, off, 16);
            }
            if (cIn == 0) {
                psP[(size_t)(rowBase + rLoc) * 64 + slotR] = rp;
                psN[(size_t)(rowBase + rLoc) * 64 + slotR] = rn;
            }
        }
    if (offd) {
        const int slotC = 2 * rb + wave;
#pragma unroll
        for (int ni = 0; ni < 4; ++ni) {
            cps[ni] += __shfl_xor(cps[ni], 16, 64);
            cps[ni] += __shfl_xor(cps[ni], 32, 64);
            cns[ni] += __shfl_xor(cns[ni], 16, 64);
            cns[ni] += __shfl_xor(cns[ni], 32, 64);
            if (q == 0) {
                const int cLoc = ni * 16 + cIn;
                psP[(size_t)(colBase + cLoc) * 64 + slotC] = cps[ni];
                psN[(size_t)(colBase + cLoc) * 64 + slotC] = cns[ni];
            }
        }
    }
}

// =====================================================================
// kernel 4: final reduce -> out[0] (16 blocks, one atomicAdd each).
// [B][64] layout: each thread sums 64 consecutive floats per array.
// =====================================================================
__global__ void __launch_bounds__(256)
k_final(const float* __restrict__ psP, const float* __restrict__ psN,
        float* __restrict__ out, int B) {
    __shared__ float red[4];
    const int r = blockIdx.x * 256 + threadIdx.x;
    const floatx4* pp = (const floatx4*)(psP + (size_t)r * 64);
    const floatx4* pn = (const floatx4*)(psN + (size_t)r * 64);
    float P = 0.f, N = 0.f;
#pragma unroll
    for (int k = 0; k < 16; ++k) {
        floatx4 a = pp[k];
        P += (a[0] + a[1]) + (a[2] + a[3]);
        floatx4 b = pn[k];
        N += (b[0] + b[1]) + (b[2] + b[3]);
    }
    float a = (P > 0.f && N > 0.f)
                  ? log1pf(P) * (1.0f / SCALE_POS) + log1pf(N) * (1.0f / SCALE_NEG)
                  : 0.f;
#pragma unroll
    for (int off = 32; off; off >>= 1) a += __shfl_down(a, off, 64);
    const int tid = threadIdx.x;
    if ((tid & 63) == 0) red[tid >> 6] = a;
    __syncthreads();
    if (tid == 0)
        atomicAdd(out, (red[0] + red[1] + red[2] + red[3]) / (float)B);
}

extern "C" void kernel_launch(void* const* d_in, const int* in_sizes, int n_in,
                              void* d_out, int out_size, void* d_ws, size_t ws_size,
                              hipStream_t stream) {
    const float* feats = (const float*)d_in[0];
    const int* labels = (const int*)d_in[1];
    const int B = in_sizes[1];            // 4096
    const int D = in_sizes[0] / B;        // 1024
    const int nb = B / 128;               // 32
    const int NT = nb * (nb + 1) / 2;     // 528
    const int total4 = B * D / 4;

    char* ws = (char*)d_ws;
    unsigned char* f8 = (unsigned char*)ws;
    size_t off = (size_t)B * D;           // 4 MB fp8
    float* pmin = (float*)(ws + off); off += (size_t)64 * B * 4;   // 1 MB, [B][64]
    float* pmax = (float*)(ws + off); off += (size_t)64 * B * 4;   // 1 MB, [B][64]
    float* psP  = (float*)(ws + off); off += (size_t)64 * B * 4;   // 1 MB, [B][64]
    float* psN  = (float*)(ws + off); off += (size_t)64 * B * 4;   // 1 MB, [B][64]
    _Float16* simh = (_Float16*)(ws + ((off + 255) & ~(size_t)255));
    float* outp = (float*)d_out;

    k_init<<<(total4 + 255) / 256, 256, 0, stream>>>(feats, f8, outp, total4);

    // 528 blocks x 256 thr — full-tile MX-fp8 GEMM + transposed stat partials
    k_gemm_h<<<NT, 256, 0, stream>>>(f8, labels, pmin, pmax, simh, D, nb);

    // pass 2: 528 blocks x 256 thr, vectorized gate prologue + partial sums
    k_sum2f<<<NT, 256, 0, stream>>>(simh, labels, pmin, pmax, psP, psN, nb, B);

    // final: 16 blocks, one atomic each
    k_final<<<B / 256, 256, 0, stream>>>(psP, psN, outp, B);
}